// Round 1
// baseline (14813.626 us; speedup 1.0000x reference)
//
#include <hip/hip_runtime.h>
#include <math.h>

#define NLAYER 6
#define DIMD 512
#define HEADS 8
#define HD 64
#define EXPERTS 8
#define SEQ 1024
#define NTOK 2048
#define FF 1024
#define VOCABN 50257

#define BM 64
#define BN 64
#define BK 16

__global__ __launch_bounds__(256) void k_embed(const int* __restrict__ ids,
                                               const float* __restrict__ E,
                                               float* __restrict__ x) {
  int i = blockIdx.x * 256 + threadIdx.x;
  if (i >= NTOK * DIMD) return;
  int n = i >> 9, d = i & 511;
  x[i] = E[(long)ids[n] * DIMD + d];
}

// C[M,N] = A[M,K] @ B[N,K]^T  (+bias, +gelu, *scale_col, +residual, +=C)
__global__ __launch_bounds__(256) void k_gemm_bt(
    const float* __restrict__ A, const float* __restrict__ B,
    float* __restrict__ C, int M, int N, int K,
    const float* __restrict__ bias, const float* __restrict__ residual,
    const float* __restrict__ scale_col, int scale_stride,
    int accum, int act) {
  __shared__ float As[BK][BM + 1];
  __shared__ float Bs[BK][BN + 1];
  int m0 = blockIdx.y * BM, n0 = blockIdx.x * BN;
  int tid = threadIdx.x;
  int tx = tid & 15, ty = tid >> 4;
  float acc[4][4] = {};
  int r = tid >> 2, c4 = (tid & 3) << 2;
  for (int k0 = 0; k0 < K; k0 += BK) {
    float4 av = make_float4(0.f, 0.f, 0.f, 0.f);
    int gm = m0 + r;
    if (gm < M) av = *(const float4*)(A + (long)gm * K + k0 + c4);
    As[c4 + 0][r] = av.x; As[c4 + 1][r] = av.y;
    As[c4 + 2][r] = av.z; As[c4 + 3][r] = av.w;
    float4 bv = make_float4(0.f, 0.f, 0.f, 0.f);
    int gn = n0 + r;
    if (gn < N) bv = *(const float4*)(B + (long)gn * K + k0 + c4);
    Bs[c4 + 0][r] = bv.x; Bs[c4 + 1][r] = bv.y;
    Bs[c4 + 2][r] = bv.z; Bs[c4 + 3][r] = bv.w;
    __syncthreads();
#pragma unroll
    for (int k = 0; k < BK; ++k) {
      float a[4], b[4];
#pragma unroll
      for (int i = 0; i < 4; ++i) a[i] = As[k][ty * 4 + i];
#pragma unroll
      for (int j = 0; j < 4; ++j) b[j] = Bs[k][tx * 4 + j];
#pragma unroll
      for (int i = 0; i < 4; ++i)
#pragma unroll
        for (int j = 0; j < 4; ++j) acc[i][j] = fmaf(a[i], b[j], acc[i][j]);
    }
    __syncthreads();
  }
#pragma unroll
  for (int i = 0; i < 4; ++i) {
    int row = m0 + ty * 4 + i;
    if (row >= M) continue;
#pragma unroll
    for (int j = 0; j < 4; ++j) {
      int col = n0 + tx * 4 + j;
      if (col >= N) continue;
      float v = acc[i][j];
      if (bias) v += bias[col];
      if (act) v = 0.5f * v * (1.f + erff(v * 0.70710678118654752f));
      if (scale_col) v *= scale_col[(long)row * scale_stride];
      if (residual) v += residual[(long)row * N + col];
      long ci = (long)row * N + col;
      if (accum) v += C[ci];
      C[ci] = v;
    }
  }
}

// one block (1 wave) per (query row, b*h); streaming softmax over 1024 keys
__global__ __launch_bounds__(64) void k_attn(const float* __restrict__ qkv,
                                             float* __restrict__ attn_o) {
  int q = blockIdx.x;
  int bh = blockIdx.y;
  int b = bh >> 3, h = bh & 7;
  int t = threadIdx.x;
  __shared__ float qs[HD];
  __shared__ float sc[SEQ];
  const float* base = qkv + (long)b * SEQ * 3 * DIMD;
  qs[t] = base[(long)q * 3 * DIMD + h * HD + t];
  __syncthreads();
  const float* kbase = base + DIMD + h * HD;
  for (int j = t; j < SEQ; j += 64) {
    const float* kr = kbase + (long)j * 3 * DIMD;
    float d = 0.f;
#pragma unroll
    for (int c = 0; c < HD; c += 4) {
      float4 kk = *(const float4*)(kr + c);
      d = fmaf(qs[c], kk.x, d);
      d = fmaf(qs[c + 1], kk.y, d);
      d = fmaf(qs[c + 2], kk.z, d);
      d = fmaf(qs[c + 3], kk.w, d);
    }
    sc[j] = d * 0.125f;
  }
  __syncthreads();
  float m = -1e30f;
  for (int j = t; j < SEQ; j += 64) m = fmaxf(m, sc[j]);
#pragma unroll
  for (int off = 32; off; off >>= 1) m = fmaxf(m, __shfl_xor(m, off));
  float s = 0.f;
  for (int j = t; j < SEQ; j += 64) {
    float e = __expf(sc[j] - m);
    sc[j] = e;
    s += e;
  }
#pragma unroll
  for (int off = 32; off; off >>= 1) s += __shfl_xor(s, off);
  float inv = 1.f / s;
  __syncthreads();
  const float* vbase = base + 2 * DIMD + h * HD + t;
  float o = 0.f;
#pragma unroll 8
  for (int j = 0; j < SEQ; ++j) o = fmaf(sc[j], vbase[(long)j * 3 * DIMD], o);
  attn_o[((long)(b * SEQ + q)) * DIMD + h * HD + t] = o * inv;
}

__global__ __launch_bounds__(64) void k_router(const float* __restrict__ x,
                                               const float* __restrict__ rw,
                                               const float* __restrict__ rb,
                                               float* __restrict__ cw) {
  int n = blockIdx.x;
  int t = threadIdx.x;
  int e = t >> 3, part = t & 7;
  __shared__ float red[64];
  const float* xr = x + (long)n * DIMD;
  const float* wr = rw + (long)e * DIMD;
  float d = 0.f;
  int c0 = part * 64;
#pragma unroll
  for (int c = 0; c < 64; c += 4) {
    float4 xv = *(const float4*)(xr + c0 + c);
    float4 wv = *(const float4*)(wr + c0 + c);
    d += xv.x * wv.x + xv.y * wv.y + xv.z * wv.z + xv.w * wv.w;
  }
  red[t] = d;
  __syncthreads();
  if (t < 8) {
    float logit = rb[t];
    for (int pp = 0; pp < 8; ++pp) logit += red[t * 8 + pp];
    red[t] = logit;
  }
  __syncthreads();
  if (t == 0) {
    float p2[8];
    float m = -1e30f;
    for (int i = 0; i < 8; ++i) m = fmaxf(m, red[i]);
    float s = 0.f;
    for (int i = 0; i < 8; ++i) { p2[i] = expf(red[i] - m); s += p2[i]; }
    for (int i = 0; i < 8; ++i) p2[i] /= s;
    int i1 = 0;
    for (int i = 1; i < 8; ++i) if (p2[i] > p2[i1]) i1 = i;
    int i2 = (i1 == 0) ? 1 : 0;
    for (int i = 0; i < 8; ++i) {
      if (i == i1 || i == i2) continue;
      if (p2[i] > p2[i2]) i2 = i;
    }
    float sum = p2[i1] + p2[i2] + 1e-8f;
    float o[8];
    for (int i = 0; i < 8; ++i) o[i] = 0.f;
    o[i1] = p2[i1] / sum;
    o[i2] = p2[i2] / sum;
    for (int i = 0; i < 8; ++i) cw[(long)n * 8 + i] = o[i];
  }
}

// BitNet 1.58b effective weight, one block per output row
__global__ __launch_bounds__(256) void k_bitw(const float* __restrict__ w,
                                              float* __restrict__ wq, int cols) {
  int row = blockIdx.x;
  int t = threadIdx.x;
  const float* wr = w + (long)row * cols;
  float s = 0.f;
  for (int c = t; c < cols; c += 256) s += fabsf(wr[c]);
  __shared__ float red[256];
  red[t] = s;
  __syncthreads();
  for (int off = 128; off; off >>= 1) {
    if (t < off) red[t] += red[t + off];
    __syncthreads();
  }
  float scale = fmaxf(red[0] / (float)cols, 1e-5f);
  float* outr = wq + (long)row * cols;
  for (int c = t; c < cols; c += 256) {
    float qv = rintf(wr[c] / scale);  // rint = half-even, matches jnp.round
    qv = fmaxf(-1.f, fminf(1.f, qv));
    outr[c] = qv * scale;
  }
}

// x_out = LN(acc + xin) * g + b, one block (128 thr) per token
__global__ __launch_bounds__(128) void k_ln(const float* __restrict__ acc,
                                            const float* __restrict__ xin,
                                            const float* __restrict__ g,
                                            const float* __restrict__ b,
                                            float* __restrict__ xout) {
  int n = blockIdx.x;
  int t = threadIdx.x;
  __shared__ float red[128];
  const float* a = acc + (long)n * DIMD;
  const float* xr = xin + (long)n * DIMD;
  float u[4];
  float s = 0.f;
#pragma unroll
  for (int i = 0; i < 4; ++i) {
    u[i] = a[t + i * 128] + xr[t + i * 128];
    s += u[i];
  }
  red[t] = s;
  __syncthreads();
  for (int off = 64; off; off >>= 1) {
    if (t < off) red[t] += red[t + off];
    __syncthreads();
  }
  float mu = red[0] / (float)DIMD;
  __syncthreads();
  float v = 0.f;
#pragma unroll
  for (int i = 0; i < 4; ++i) {
    float d = u[i] - mu;
    v += d * d;
  }
  red[t] = v;
  __syncthreads();
  for (int off = 64; off; off >>= 1) {
    if (t < off) red[t] += red[t + off];
    __syncthreads();
  }
  float inv = 1.f / sqrtf(red[0] / (float)DIMD + 1e-5f);
#pragma unroll
  for (int i = 0; i < 4; ++i) {
    int c = t + i * 128;
    xout[(long)n * DIMD + c] = (u[i] - mu) * inv * g[c] + b[c];
  }
}

extern "C" void kernel_launch(void* const* d_in, const int* in_sizes, int n_in,
                              void* d_out, int out_size, void* d_ws, size_t ws_size,
                              hipStream_t stream) {
  const int* ids = (const int*)d_in[0];
  const float* embed = (const float*)d_in[1];
  const float* qkv_w = (const float*)d_in[2];
  const float* out_w = (const float*)d_in[3];
  const float* router_w = (const float*)d_in[4];
  const float* router_b = (const float*)d_in[5];
  const float* w1 = (const float*)d_in[6];
  const float* b1 = (const float*)d_in[7];
  const float* w2 = (const float*)d_in[8];
  const float* b2 = (const float*)d_in[9];
  const float* ln_g = (const float*)d_in[10];
  const float* ln_b = (const float*)d_in[11];
  const float* head_w = (const float*)d_in[12];
  float* out = (float*)d_out;

  float* p = (float*)d_ws;
  float* xA = p; p += NTOK * DIMD;
  float* xB = p; p += NTOK * DIMD;
  float* qkvb = p; p += (long)NTOK * 3 * DIMD;
  float* attn_o = p; p += NTOK * DIMD;
  float* we1 = p; p += (long)EXPERTS * FF * DIMD;
  float* we2 = p; p += (long)EXPERTS * DIMD * FF;
  float* hbuf = p; p += (long)NTOK * FF;
  float* macc = p; p += NTOK * DIMD;
  float* cw = p; p += NTOK * EXPERTS;
  size_t need = (size_t)(p - (float*)d_ws) * sizeof(float);
  if (ws_size < need) return;  // insufficient scratch; fail loudly via validation

  k_embed<<<(NTOK * DIMD + 255) / 256, 256, 0, stream>>>(ids, embed, xA);

  for (int l = 0; l < NLAYER; ++l) {
    const float* qw = qkv_w + (long)l * 3 * DIMD * DIMD;
    const float* ow = out_w + (long)l * DIMD * DIMD;
    // qkv = x @ qkv_w^T
    k_gemm_bt<<<dim3((3 * DIMD) / BN, NTOK / BM), 256, 0, stream>>>(
        xA, qw, qkvb, NTOK, 3 * DIMD, DIMD, nullptr, nullptr, nullptr, 0, 0, 0);
    k_attn<<<dim3(SEQ, 2 * HEADS), 64, 0, stream>>>(qkvb, attn_o);
    // xB = attn_o @ out_w^T + xA
    k_gemm_bt<<<dim3(DIMD / BN, NTOK / BM), 256, 0, stream>>>(
        attn_o, ow, xB, NTOK, DIMD, DIMD, nullptr, xA, nullptr, 0, 0, 0);
    // router -> combine weights
    k_router<<<NTOK, 64, 0, stream>>>(xB, router_w + (long)l * EXPERTS * DIMD,
                                      router_b + l * EXPERTS, cw);
    // BitNet effective weights
    k_bitw<<<EXPERTS * FF, 256, 0, stream>>>(w1 + (long)l * EXPERTS * FF * DIMD, we1, DIMD);
    k_bitw<<<EXPERTS * DIMD, 256, 0, stream>>>(w2 + (long)l * EXPERTS * DIMD * FF, we2, FF);
    // dense experts, sequential accumulation (deterministic)
    for (int e = 0; e < EXPERTS; ++e) {
      k_gemm_bt<<<dim3(FF / BN, NTOK / BM), 256, 0, stream>>>(
          xB, we1 + (long)e * FF * DIMD, hbuf, NTOK, FF, DIMD,
          b1 + ((long)l * EXPERTS + e) * FF, nullptr, nullptr, 0, 0, 1);
      k_gemm_bt<<<dim3(DIMD / BN, NTOK / BM), 256, 0, stream>>>(
          hbuf, we2 + (long)e * DIMD * FF, macc, NTOK, DIMD, FF,
          b2 + ((long)l * EXPERTS + e) * DIMD, nullptr, cw + e, EXPERTS,
          (e > 0) ? 1 : 0, 0);
    }
    k_ln<<<NTOK, 128, 0, stream>>>(macc, xB, ln_g + l * DIMD, ln_b + l * DIMD, xA);
  }
  // logits = x @ head_w^T
  k_gemm_bt<<<dim3((VOCABN + BN - 1) / BN, NTOK / BM), 256, 0, stream>>>(
      xA, head_w, out, NTOK, VOCABN, DIMD, nullptr, nullptr, nullptr, 0, 0, 0);
}

// Round 3
// 6856.813 us; speedup vs baseline: 2.1604x; 2.1604x over previous
//
#include <hip/hip_runtime.h>
#include <math.h>
#include <stdint.h>

#define NLAYER 6
#define DIMD 512
#define HEADS 8
#define HD 64
#define EXPERTS 8
#define SEQ 1024
#define NTOK 2048
#define FF 1024
#define VOCABN 50257
#define HROWS 50304  // 393*128 zero-padded head rows

typedef __bf16 bf16;
typedef __bf16 bf16x8 __attribute__((ext_vector_type(8)));
typedef float f32x4 __attribute__((ext_vector_type(4)));

__device__ __forceinline__ void gl_lds16(const void* g, void* l) {
  __builtin_amdgcn_global_load_lds(
      (const __attribute__((address_space(1))) void*)(uintptr_t)g,
      (__attribute__((address_space(3))) void*)(uintptr_t)l, 16, 0, 0);
}

// ============ multi-pass split-bf16 MFMA GEMM: C = A @ Bt^T ============
// A,B given as up to 3 bf16 split terms (A ~= A0+A1+A2). Each pass does a
// full K-loop MFMA GEMM with a selected (Ai,Bj) pair, accumulating into the
// same f32 acc. modes:
//  0: 1 pass (0,0)                      -- plain bf16 (head)
//  1: 6 passes (0,0)(0,1)(1,0)(1,1)(0,2)(2,0)  -- ~f32 (A3 x B3)
//  2: 3 passes (0,0)(1,0)(2,0)          -- ~f32, B exact (bitnet q)
//  3: 2 passes (0,0)(1,0)               -- A 2-split, B exact
//  4: 5 passes (0,0)(0,1)(1,0)(0,2)(1,1) -- A 2-split x B 3-split
// epilogue: v = acc [*colScale[n]] [+bias[n]] [gelu] [+residual]; writes
// optional f32 C and up to 3 bf16 split outputs.
__global__ __launch_bounds__(256) void k_mfma_gemm(
    const bf16* __restrict__ A0, const bf16* __restrict__ A1,
    const bf16* __restrict__ A2, const bf16* __restrict__ B0,
    const bf16* __restrict__ B1, const bf16* __restrict__ B2,
    float* __restrict__ Cf, bf16* __restrict__ Cb0, bf16* __restrict__ Cb1,
    bf16* __restrict__ Cb2, int M, int N, int K,
    long sA, long sB, long sCf, long sCb,
    const float* __restrict__ colScale, int csStride,
    const float* __restrict__ bias, int biasStride,
    const float* __restrict__ residual, int act, int mode) {
  __shared__ __align__(16) bf16 As[128 * 32];
  __shared__ __align__(16) bf16 Bs[128 * 32];
  int tid = threadIdx.x;
  int z = blockIdx.z;
  int m0 = blockIdx.x * 128, n0 = blockIdx.y * 128;
  int w = tid >> 6, lane = tid & 63;
  int wm = (w >> 1) * 64, wn = (w & 1) * 64;
  int r15 = lane & 15, kg = lane >> 4;

  const bf16* PA[3] = {A0, A1, A2};
  const bf16* PB[3] = {B0, B1, B2};
  int pa[6] = {0, 0, 0, 0, 0, 0};
  int pb[6] = {0, 0, 0, 0, 0, 0};
  int np = 1;
  if (mode == 1) {
    np = 6;
    pa[1] = 0; pb[1] = 1; pa[2] = 1; pb[2] = 0; pa[3] = 1; pb[3] = 1;
    pa[4] = 0; pb[4] = 2; pa[5] = 2; pb[5] = 0;
  } else if (mode == 2) {
    np = 3; pa[1] = 1; pa[2] = 2;
  } else if (mode == 3) {
    np = 2; pa[1] = 1;
  } else if (mode == 4) {
    np = 5;
    pa[1] = 0; pb[1] = 1; pa[2] = 1; pb[2] = 0; pa[3] = 0; pb[3] = 2;
    pa[4] = 1; pb[4] = 1;
  }

  f32x4 acc[4][4] = {};
  int srow = tid >> 2;
  int scol = (tid & 3) * 8;
  bf16* la0 = &As[tid * 8];
  bf16* la1 = &As[64 * 32 + tid * 8];
  bf16* lb0 = &Bs[tid * 8];
  bf16* lb1 = &Bs[64 * 32 + tid * 8];

  for (int p = 0; p < np; ++p) {
    const bf16* Az = PA[pa[p]] + (long)z * sA;
    const bf16* Bz = PB[pb[p]] + (long)z * sB;
    const bf16* ga0 = Az + (long)(m0 + srow) * K + scol;
    const bf16* ga1 = Az + (long)(m0 + 64 + srow) * K + scol;
    const bf16* gb0 = Bz + (long)(n0 + srow) * K + scol;
    const bf16* gb1 = Bz + (long)(n0 + 64 + srow) * K + scol;
    for (int k0 = 0; k0 < K; k0 += 32) {
      gl_lds16(ga0, la0);
      gl_lds16(ga1, la1);
      gl_lds16(gb0, lb0);
      gl_lds16(gb1, lb1);
      ga0 += 32; ga1 += 32; gb0 += 32; gb1 += 32;
      __syncthreads();  // drains vmcnt: tiles ready
      bf16x8 af[4], bfr[4];
#pragma unroll
      for (int mi = 0; mi < 4; ++mi)
        af[mi] = *(const bf16x8*)&As[(wm + mi * 16 + r15) * 32 + kg * 8];
#pragma unroll
      for (int ni = 0; ni < 4; ++ni)
        bfr[ni] = *(const bf16x8*)&Bs[(wn + ni * 16 + r15) * 32 + kg * 8];
#pragma unroll
      for (int mi = 0; mi < 4; ++mi)
#pragma unroll
        for (int ni = 0; ni < 4; ++ni)
          acc[mi][ni] = __builtin_amdgcn_mfma_f32_16x16x32_bf16(
              af[mi], bfr[ni], acc[mi][ni], 0, 0, 0);
      __syncthreads();  // reads done before next overwrite
    }
  }

  // C/D layout: col=lane&15, row=(lane>>4)*4+reg  [m89]
#pragma unroll
  for (int mi = 0; mi < 4; ++mi) {
    int rbase = m0 + wm + mi * 16 + kg * 4;
#pragma unroll
    for (int ni = 0; ni < 4; ++ni) {
      int col = n0 + wn + ni * 16 + r15;
      if (col >= N) continue;
      float scl = colScale ? colScale[z * csStride + col] : 1.f;
      float bv = bias ? bias[z * biasStride + col] : 0.f;
#pragma unroll
      for (int reg = 0; reg < 4; ++reg) {
        int row = rbase + reg;
        float v = acc[mi][ni][reg] * scl + bv;
        if (act) v = 0.5f * v * (1.f + erff(v * 0.70710678118654752f));
        if (residual) v += residual[(long)row * N + col];
        long ci = (long)row * N + col;
        if (Cf) Cf[z * sCf + ci] = v;
        if (Cb0) {
          bf16 h0 = (bf16)v;
          Cb0[z * sCb + ci] = h0;
          if (Cb1) {
            float r = v - (float)h0;
            bf16 h1 = (bf16)r;
            Cb1[z * sCb + ci] = h1;
            if (Cb2) Cb2[z * sCb + ci] = (bf16)(r - (float)h1);
          }
        }
      }
    }
  }
}

// ---------------- helpers ----------------
__global__ __launch_bounds__(256) void k_embed(const int* __restrict__ ids,
                                               const float* __restrict__ E,
                                               float* __restrict__ xf,
                                               bf16* __restrict__ x0,
                                               bf16* __restrict__ x1,
                                               bf16* __restrict__ x2) {
  int i = blockIdx.x * 256 + threadIdx.x;
  if (i >= NTOK * DIMD) return;
  int n = i >> 9, d = i & 511;
  float v = E[(long)ids[n] * DIMD + d];
  xf[i] = v;
  bf16 b0 = (bf16)v;
  float r = v - (float)b0;
  bf16 b1 = (bf16)r;
  x0[i] = b0; x1[i] = b1; x2[i] = (bf16)(r - (float)b1);
}

// f32 -> 3-term bf16 split, 8 elems/thread
__global__ __launch_bounds__(256) void k_split3(const float* __restrict__ s,
                                                bf16* __restrict__ d0,
                                                bf16* __restrict__ d1,
                                                bf16* __restrict__ d2, long n8) {
  long i = (long)blockIdx.x * 256 + threadIdx.x;
  if (i >= n8) return;
  const float4* s4 = (const float4*)s;
  float4 a = s4[2 * i], b = s4[2 * i + 1];
  float vv[8] = {a.x, a.y, a.z, a.w, b.x, b.y, b.z, b.w};
  bf16x8 o0, o1, o2;
#pragma unroll
  for (int j = 0; j < 8; ++j) {
    float v = vv[j];
    bf16 h0 = (bf16)v;
    float r = v - (float)h0;
    bf16 h1 = (bf16)r;
    o0[j] = h0; o1[j] = h1; o2[j] = (bf16)(r - (float)h1);
  }
  ((bf16x8*)d0)[i] = o0;
  ((bf16x8*)d1)[i] = o1;
  ((bf16x8*)d2)[i] = o2;
}

// head_w [50257,512] f32 -> bf16 hi, zero-padded to HROWS rows
__global__ __launch_bounds__(256) void k_headconv(const float* __restrict__ s,
                                                  bf16* __restrict__ d) {
  long i = (long)blockIdx.x * 256 + threadIdx.x;
  long n8 = (long)HROWS * DIMD / 8;
  if (i >= n8) return;
  long row = i / (DIMD / 8);
  bf16x8 o;
  if (row < VOCABN) {
    const float4* s4 = (const float4*)s;
    float4 a = s4[2 * i], b = s4[2 * i + 1];
    o[0] = (bf16)a.x; o[1] = (bf16)a.y; o[2] = (bf16)a.z; o[3] = (bf16)a.w;
    o[4] = (bf16)b.x; o[5] = (bf16)b.y; o[6] = (bf16)b.z; o[7] = (bf16)b.w;
  } else {
    o = (bf16x8)(bf16)0.f;
  }
  ((bf16x8*)d)[i] = o;
}

// one wave per (q, b*h); streaming softmax over 1024 keys (f32 qkv in)
__global__ __launch_bounds__(64) void k_attn(const float* __restrict__ qkv,
                                             bf16* __restrict__ a0,
                                             bf16* __restrict__ a1) {
  int q = blockIdx.x;
  int bh = blockIdx.y;
  int b = bh >> 3, h = bh & 7;
  int t = threadIdx.x;
  __shared__ float qs[HD];
  __shared__ float sc[SEQ];
  const float* base = qkv + (long)b * SEQ * 3 * DIMD;
  qs[t] = base[(long)q * 3 * DIMD + h * HD + t];
  __syncthreads();
  const float* kbase = base + DIMD + h * HD;
  for (int j = t; j < SEQ; j += 64) {
    const float* kr = kbase + (long)j * 3 * DIMD;
    float d = 0.f;
#pragma unroll
    for (int c = 0; c < HD; c += 4) {
      float4 kk = *(const float4*)(kr + c);
      d = fmaf(qs[c], kk.x, d);
      d = fmaf(qs[c + 1], kk.y, d);
      d = fmaf(qs[c + 2], kk.z, d);
      d = fmaf(qs[c + 3], kk.w, d);
    }
    sc[j] = d * 0.125f;
  }
  __syncthreads();
  float m = -1e30f;
  for (int j = t; j < SEQ; j += 64) m = fmaxf(m, sc[j]);
#pragma unroll
  for (int off = 32; off; off >>= 1) m = fmaxf(m, __shfl_xor(m, off));
  float s = 0.f;
  for (int j = t; j < SEQ; j += 64) {
    float e = __expf(sc[j] - m);
    sc[j] = e;
    s += e;
  }
#pragma unroll
  for (int off = 32; off; off >>= 1) s += __shfl_xor(s, off);
  float inv = 1.f / s;
  __syncthreads();
  const float* vbase = base + 2 * DIMD + h * HD + t;
  float o = 0.f;
#pragma unroll 8
  for (int j = 0; j < SEQ; ++j) o = fmaf(sc[j], vbase[(long)j * 3 * DIMD], o);
  o *= inv;
  long oi = ((long)(b * SEQ + q)) * DIMD + h * HD + t;
  bf16 h0 = (bf16)o;
  a0[oi] = h0;
  a1[oi] = (bf16)(o - (float)h0);
}

__global__ __launch_bounds__(64) void k_router(const float* __restrict__ x,
                                               const float* __restrict__ rw,
                                               const float* __restrict__ rb,
                                               float* __restrict__ cw) {
  int n = blockIdx.x;
  int t = threadIdx.x;
  int e = t >> 3, part = t & 7;
  __shared__ float red[64];
  const float* xr = x + (long)n * DIMD;
  const float* wr = rw + (long)e * DIMD;
  float d = 0.f;
  int c0 = part * 64;
#pragma unroll
  for (int c = 0; c < 64; c += 4) {
    float4 xv = *(const float4*)(xr + c0 + c);
    float4 wv = *(const float4*)(wr + c0 + c);
    d += xv.x * wv.x + xv.y * wv.y + xv.z * wv.z + xv.w * wv.w;
  }
  red[t] = d;
  __syncthreads();
  if (t < 8) {
    float logit = rb[t];
    for (int pp = 0; pp < 8; ++pp) logit += red[t * 8 + pp];
    red[t] = logit;
  }
  __syncthreads();
  if (t == 0) {
    float p2[8];
    float m = -1e30f;
    for (int i = 0; i < 8; ++i) m = fmaxf(m, red[i]);
    float s = 0.f;
    for (int i = 0; i < 8; ++i) { p2[i] = expf(red[i] - m); s += p2[i]; }
    for (int i = 0; i < 8; ++i) p2[i] /= s;
    int i1 = 0;
    for (int i = 1; i < 8; ++i) if (p2[i] > p2[i1]) i1 = i;
    int i2 = (i1 == 0) ? 1 : 0;
    for (int i = 0; i < 8; ++i) {
      if (i == i1 || i == i2) continue;
      if (p2[i] > p2[i2]) i2 = i;
    }
    float sum = p2[i1] + p2[i2] + 1e-8f;
    float o[8];
    for (int i = 0; i < 8; ++i) o[i] = 0.f;
    o[i1] = p2[i1] / sum;
    o[i2] = p2[i2] / sum;
    for (int i = 0; i < 8; ++i) cw[(long)n * 8 + i] = o[i];
  }
}

// BitNet: q in {-1,0,1} (exact bf16) + per-row f32 scale
__global__ __launch_bounds__(256) void k_bitw(const float* __restrict__ w,
                                              bf16* __restrict__ q,
                                              float* __restrict__ s, int cols) {
  int row = blockIdx.x;
  int t = threadIdx.x;
  const float* wr = w + (long)row * cols;
  float acc = 0.f;
  for (int c = t; c < cols; c += 256) acc += fabsf(wr[c]);
  __shared__ float red[256];
  red[t] = acc;
  __syncthreads();
  for (int off = 128; off; off >>= 1) {
    if (t < off) red[t] += red[t + off];
    __syncthreads();
  }
  float scale = fmaxf(red[0] / (float)cols, 1e-5f);
  if (t == 0) s[row] = scale;
  bf16* outr = q + (long)row * cols;
  for (int c = t; c < cols; c += 256) {
    float qv = rintf(wr[c] / scale);  // RNE, matches jnp.round
    qv = fmaxf(-1.f, fminf(1.f, qv));
    outr[c] = (bf16)qv;
  }
}

// combine top-2 experts (f32 y), add residual, LayerNorm -> f32 + 3-split
__global__ __launch_bounds__(128) void k_lncomb(
    const float* __restrict__ yall, const float* __restrict__ cwp,
    const float* __restrict__ xBf, const float* __restrict__ g,
    const float* __restrict__ b, float* __restrict__ xof,
    bf16* __restrict__ x0, bf16* __restrict__ x1, bf16* __restrict__ x2) {
  int n = blockIdx.x;
  int t = threadIdx.x;
  __shared__ float red[128];
  float cw[8];
#pragma unroll
  for (int e = 0; e < 8; ++e) cw[e] = cwp[(long)n * 8 + e];
  float u[4];
  float s = 0.f;
#pragma unroll
  for (int i = 0; i < 4; ++i) {
    int d = t + i * 128;
    float v = xBf[(long)n * DIMD + d];
#pragma unroll
    for (int e = 0; e < 8; ++e)
      if (cw[e] != 0.f) v += cw[e] * yall[((long)e * NTOK + n) * DIMD + d];
    u[i] = v;
    s += v;
  }
  red[t] = s;
  __syncthreads();
  for (int off = 64; off; off >>= 1) {
    if (t < off) red[t] += red[t + off];
    __syncthreads();
  }
  float mu = red[0] / (float)DIMD;
  __syncthreads();
  float var = 0.f;
#pragma unroll
  for (int i = 0; i < 4; ++i) {
    float d = u[i] - mu;
    var += d * d;
  }
  red[t] = var;
  __syncthreads();
  for (int off = 64; off; off >>= 1) {
    if (t < off) red[t] += red[t + off];
    __syncthreads();
  }
  float inv = 1.f / sqrtf(red[0] / (float)DIMD + 1e-5f);
#pragma unroll
  for (int i = 0; i < 4; ++i) {
    int c = t + i * 128;
    float v = (u[i] - mu) * inv * g[c] + b[c];
    long oi = (long)n * DIMD + c;
    xof[oi] = v;
    bf16 b0 = (bf16)v;
    float r = v - (float)b0;
    bf16 b1 = (bf16)r;
    x0[oi] = b0; x1[oi] = b1; x2[oi] = (bf16)(r - (float)b1);
  }
}

extern "C" void kernel_launch(void* const* d_in, const int* in_sizes, int n_in,
                              void* d_out, int out_size, void* d_ws, size_t ws_size,
                              hipStream_t stream) {
  const int* ids = (const int*)d_in[0];
  const float* embed = (const float*)d_in[1];
  const float* qkv_w = (const float*)d_in[2];
  const float* out_w = (const float*)d_in[3];
  const float* router_w = (const float*)d_in[4];
  const float* router_b = (const float*)d_in[5];
  const float* w1 = (const float*)d_in[6];
  const float* b1 = (const float*)d_in[7];
  const float* w2 = (const float*)d_in[8];
  const float* b2 = (const float*)d_in[9];
  const float* ln_g = (const float*)d_in[10];
  const float* ln_b = (const float*)d_in[11];
  const float* head_w = (const float*)d_in[12];
  float* out = (float*)d_out;

  char* base = (char*)d_ws;
  size_t off = 0;
  auto alloc = [&](size_t bytes) -> void* {
    void* p = base + off;
    off += (bytes + 255) & ~(size_t)255;
    return p;
  };
  const size_t ND = (size_t)NTOK * DIMD;
  float* xAf = (float*)alloc(ND * 4);
  float* xBf = (float*)alloc(ND * 4);
  float* qkvb = (float*)alloc(ND * 3 * 4);
  float* cw = (float*)alloc((size_t)NTOK * EXPERTS * 4);
  bf16* xA0 = (bf16*)alloc(ND * 2);
  bf16* xA1 = (bf16*)alloc(ND * 2);
  bf16* xA2 = (bf16*)alloc(ND * 2);
  bf16* xB0 = (bf16*)alloc(ND * 2);
  bf16* xB1 = (bf16*)alloc(ND * 2);
  bf16* xB2 = (bf16*)alloc(ND * 2);
  bf16* at0 = (bf16*)alloc(ND * 2);
  bf16* at1 = (bf16*)alloc(ND * 2);
  bf16* qw0 = (bf16*)alloc((size_t)3 * DIMD * DIMD * 2);
  bf16* qw1 = (bf16*)alloc((size_t)3 * DIMD * DIMD * 2);
  bf16* qw2 = (bf16*)alloc((size_t)3 * DIMD * DIMD * 2);
  bf16* ow0 = (bf16*)alloc((size_t)DIMD * DIMD * 2);
  bf16* ow1 = (bf16*)alloc((size_t)DIMD * DIMD * 2);
  bf16* ow2 = (bf16*)alloc((size_t)DIMD * DIMD * 2);
  size_t Ustart = off;
  bf16* we1q = (bf16*)alloc((size_t)EXPERTS * FF * DIMD * 2);
  float* s1 = (float*)alloc((size_t)EXPERTS * FF * 4);
  bf16* we2q = (bf16*)alloc((size_t)EXPERTS * DIMD * FF * 2);
  float* s2 = (float*)alloc((size_t)EXPERTS * DIMD * 4);
  bf16* h0 = (bf16*)alloc((size_t)EXPERTS * NTOK * FF * 2);
  bf16* h1 = (bf16*)alloc((size_t)EXPERTS * NTOK * FF * 2);
  float* yall = (float*)alloc((size_t)EXPERTS * ND * 4);
  size_t headBytes = (size_t)HROWS * DIMD * 2;
  if (off - Ustart < headBytes) off = Ustart + ((headBytes + 255) & ~(size_t)255);
  bf16* hw0 = (bf16*)(base + Ustart);  // overlays expert buffers (dead by head)
  if (ws_size < off) return;

  k_embed<<<(NTOK * DIMD + 255) / 256, 256, 0, stream>>>(ids, embed, xAf, xA0,
                                                         xA1, xA2);

  for (int l = 0; l < NLAYER; ++l) {
    const float* qw = qkv_w + (long)l * 3 * DIMD * DIMD;
    const float* ow = out_w + (long)l * DIMD * DIMD;
    long nq8 = (long)3 * DIMD * DIMD / 8;
    long no8 = (long)DIMD * DIMD / 8;
    k_split3<<<(int)((nq8 + 255) / 256), 256, 0, stream>>>(qw, qw0, qw1, qw2, nq8);
    k_split3<<<(int)((no8 + 255) / 256), 256, 0, stream>>>(ow, ow0, ow1, ow2, no8);
    // qkv = x @ qkv_w^T  (mode 1: ~f32, f32 out)
    k_mfma_gemm<<<dim3(NTOK / 128, (3 * DIMD) / 128, 1), 256, 0, stream>>>(
        xA0, xA1, xA2, qw0, qw1, qw2, qkvb, nullptr, nullptr, nullptr,
        NTOK, 3 * DIMD, DIMD, 0, 0, 0, 0, nullptr, 0, nullptr, 0, nullptr, 0, 1);
    k_attn<<<dim3(SEQ, 2 * HEADS), 64, 0, stream>>>(qkvb, at0, at1);
    // xB = attn_o @ out_w^T + xA  (mode 4; f32 + 3-split out)
    k_mfma_gemm<<<dim3(NTOK / 128, DIMD / 128, 1), 256, 0, stream>>>(
        at0, at1, nullptr, ow0, ow1, ow2, xBf, xB0, xB1, xB2,
        NTOK, DIMD, DIMD, 0, 0, 0, 0, nullptr, 0, nullptr, 0, xAf, 0, 4);
    k_router<<<NTOK, 64, 0, stream>>>(xBf, router_w + (long)l * EXPERTS * DIMD,
                                      router_b + l * EXPERTS, cw);
    k_bitw<<<EXPERTS * FF, 256, 0, stream>>>(w1 + (long)l * EXPERTS * FF * DIMD,
                                             we1q, s1, DIMD);
    k_bitw<<<EXPERTS * DIMD, 256, 0, stream>>>(
        w2 + (long)l * EXPERTS * DIMD * FF, we2q, s2, FF);
    // h[e] = gelu((xB @ q1[e]^T)*s1 + b1)  (mode 2; 2-split bf16 out)
    k_mfma_gemm<<<dim3(NTOK / 128, FF / 128, EXPERTS), 256, 0, stream>>>(
        xB0, xB1, xB2, we1q, nullptr, nullptr, nullptr, h0, h1, nullptr,
        NTOK, FF, DIMD, 0, (long)FF * DIMD, 0, (long)NTOK * FF,
        s1, FF, b1 + (long)l * EXPERTS * FF, FF, nullptr, 1, 2);
    // y[e] = (h[e] @ q2[e]^T)*s2 + b2  (mode 3; f32 out)
    k_mfma_gemm<<<dim3(NTOK / 128, DIMD / 128, EXPERTS), 256, 0, stream>>>(
        h0, h1, nullptr, we2q, nullptr, nullptr, yall, nullptr, nullptr, nullptr,
        NTOK, DIMD, FF, (long)NTOK * FF, (long)DIMD * FF, (long)ND, 0,
        s2, DIMD, b2 + (long)l * EXPERTS * DIMD, DIMD, nullptr, 0, 3);
    k_lncomb<<<NTOK, 128, 0, stream>>>(yall, cw, xBf, ln_g + l * DIMD,
                                       ln_b + l * DIMD, xAf, xA0, xA1, xA2);
  }
  // head: logits = x @ head_w^T  (mode 0: plain bf16)
  long nh8 = (long)HROWS * DIMD / 8;
  k_headconv<<<(int)((nh8 + 255) / 256), 256, 0, stream>>>(head_w, hw0);
  k_mfma_gemm<<<dim3(NTOK / 128, HROWS / 128, 1), 256, 0, stream>>>(
      xA0, nullptr, nullptr, hw0, nullptr, nullptr, out, nullptr, nullptr,
      nullptr, NTOK, VOCABN, DIMD, 0, 0, 0, 0, nullptr, 0, nullptr, 0,
      nullptr, 0, 0);
}

// Round 4
// 3020.678 us; speedup vs baseline: 4.9041x; 2.2700x over previous
//
#include <hip/hip_runtime.h>
#include <math.h>
#include <stdint.h>

#define NLAYER 6
#define DIMD 512
#define HEADS 8
#define HD 64
#define EXPERTS 8
#define SEQ 1024
#define NTOK 2048
#define FF 1024
#define VOCABN 50257
#define HROWS 50304  // 393*128 zero-padded head rows

typedef __bf16 bf16;
typedef __bf16 bf16x8 __attribute__((ext_vector_type(8)));
typedef float f32x4 __attribute__((ext_vector_type(4)));

__device__ __forceinline__ void gl_lds16(const void* g, void* l) {
  __builtin_amdgcn_global_load_lds(
      (const __attribute__((address_space(1))) void*)(uintptr_t)g,
      (__attribute__((address_space(3))) void*)(uintptr_t)l, 16, 0, 0);
}

// ============ multi-pass split-bf16 MFMA GEMM: C = A @ Bt^T ============
// modes:
//  0: 1 pass (0,0)
//  1: 6 passes (0,0)(0,1)(1,0)(1,1)(0,2)(2,0)   ~f32 3x3
//  2: 3 passes (0,0)(1,0)(2,0)                  A 3-split, B exact
//  3: 2 passes (0,0)(1,0)                       A 2-split, B exact
//  4: 5 passes (0,0)(0,1)(1,0)(0,2)(1,1)        A 2-split x B 3-split
//  5: 3 passes (0,0)(0,1)(1,0)                  A 2-split x B 2-split
__global__ __launch_bounds__(256) void k_mfma_gemm(
    const bf16* __restrict__ A0, const bf16* __restrict__ A1,
    const bf16* __restrict__ A2, const bf16* __restrict__ B0,
    const bf16* __restrict__ B1, const bf16* __restrict__ B2,
    float* __restrict__ Cf, bf16* __restrict__ Cb0, bf16* __restrict__ Cb1,
    bf16* __restrict__ Cb2, int M, int N, int K,
    long sA, long sB, long sCf, long sCb,
    const float* __restrict__ colScale, int csStride,
    const float* __restrict__ bias, int biasStride,
    const float* __restrict__ residual, int act, int mode) {
  __shared__ __align__(16) bf16 As[128 * 32];
  __shared__ __align__(16) bf16 Bs[128 * 32];
  int tid = threadIdx.x;
  int z = blockIdx.z;
  int m0 = blockIdx.x * 128, n0 = blockIdx.y * 128;
  int w = tid >> 6, lane = tid & 63;
  int wm = (w >> 1) * 64, wn = (w & 1) * 64;
  int r15 = lane & 15, kg = lane >> 4;

  const bf16* PA[3] = {A0, A1, A2};
  const bf16* PB[3] = {B0, B1, B2};
  int pa[6] = {0, 0, 0, 0, 0, 0};
  int pb[6] = {0, 0, 0, 0, 0, 0};
  int np = 1;
  if (mode == 1) {
    np = 6;
    pa[1] = 0; pb[1] = 1; pa[2] = 1; pb[2] = 0; pa[3] = 1; pb[3] = 1;
    pa[4] = 0; pb[4] = 2; pa[5] = 2; pb[5] = 0;
  } else if (mode == 2) {
    np = 3; pa[1] = 1; pa[2] = 2;
  } else if (mode == 3) {
    np = 2; pa[1] = 1;
  } else if (mode == 4) {
    np = 5;
    pa[1] = 0; pb[1] = 1; pa[2] = 1; pb[2] = 0; pa[3] = 0; pb[3] = 2;
    pa[4] = 1; pb[4] = 1;
  } else if (mode == 5) {
    np = 3;
    pa[1] = 0; pb[1] = 1; pa[2] = 1; pb[2] = 0;
  }

  f32x4 acc[4][4] = {};
  int srow = tid >> 2;
  int scol = (tid & 3) * 8;
  bf16* la0 = &As[tid * 8];
  bf16* la1 = &As[64 * 32 + tid * 8];
  bf16* lb0 = &Bs[tid * 8];
  bf16* lb1 = &Bs[64 * 32 + tid * 8];

  for (int p = 0; p < np; ++p) {
    const bf16* Az = PA[pa[p]] + (long)z * sA;
    const bf16* Bz = PB[pb[p]] + (long)z * sB;
    const bf16* ga0 = Az + (long)(m0 + srow) * K + scol;
    const bf16* ga1 = Az + (long)(m0 + 64 + srow) * K + scol;
    const bf16* gb0 = Bz + (long)(n0 + srow) * K + scol;
    const bf16* gb1 = Bz + (long)(n0 + 64 + srow) * K + scol;
    for (int k0 = 0; k0 < K; k0 += 32) {
      gl_lds16(ga0, la0);
      gl_lds16(ga1, la1);
      gl_lds16(gb0, lb0);
      gl_lds16(gb1, lb1);
      ga0 += 32; ga1 += 32; gb0 += 32; gb1 += 32;
      __syncthreads();  // drains vmcnt: tiles ready
      bf16x8 af[4], bfr[4];
#pragma unroll
      for (int mi = 0; mi < 4; ++mi)
        af[mi] = *(const bf16x8*)&As[(wm + mi * 16 + r15) * 32 + kg * 8];
#pragma unroll
      for (int ni = 0; ni < 4; ++ni)
        bfr[ni] = *(const bf16x8*)&Bs[(wn + ni * 16 + r15) * 32 + kg * 8];
#pragma unroll
      for (int mi = 0; mi < 4; ++mi)
#pragma unroll
        for (int ni = 0; ni < 4; ++ni)
          acc[mi][ni] = __builtin_amdgcn_mfma_f32_16x16x32_bf16(
              af[mi], bfr[ni], acc[mi][ni], 0, 0, 0);
      __syncthreads();  // reads done before next overwrite
    }
  }

  // C/D layout: col=lane&15, row=(lane>>4)*4+reg  [m89]
#pragma unroll
  for (int mi = 0; mi < 4; ++mi) {
    int rbase = m0 + wm + mi * 16 + kg * 4;
#pragma unroll
    for (int ni = 0; ni < 4; ++ni) {
      int col = n0 + wn + ni * 16 + r15;
      if (col >= N) continue;
      float scl = colScale ? colScale[z * csStride + col] : 1.f;
      float bv = bias ? bias[z * biasStride + col] : 0.f;
#pragma unroll
      for (int reg = 0; reg < 4; ++reg) {
        int row = rbase + reg;
        float v = acc[mi][ni][reg] * scl + bv;
        if (act) v = 0.5f * v * (1.f + erff(v * 0.70710678118654752f));
        if (residual) v += residual[(long)row * N + col];
        long ci = (long)row * N + col;
        if (Cf) Cf[z * sCf + ci] = v;
        if (Cb0) {
          bf16 h0 = (bf16)v;
          Cb0[z * sCb + ci] = h0;
          if (Cb1) {
            float r = v - (float)h0;
            bf16 h1 = (bf16)r;
            Cb1[z * sCb + ci] = h1;
            if (Cb2) Cb2[z * sCb + ci] = (bf16)(r - (float)h1);
          }
        }
      }
    }
  }
}

// ---------------- helpers ----------------
__global__ __launch_bounds__(256) void k_embed(const int* __restrict__ ids,
                                               const float* __restrict__ E,
                                               float* __restrict__ xf,
                                               bf16* __restrict__ x0,
                                               bf16* __restrict__ x1,
                                               bf16* __restrict__ x2) {
  int i = blockIdx.x * 256 + threadIdx.x;
  if (i >= NTOK * DIMD) return;
  int n = i >> 9, d = i & 511;
  float v = E[(long)ids[n] * DIMD + d];
  xf[i] = v;
  bf16 b0 = (bf16)v;
  float r = v - (float)b0;
  bf16 b1 = (bf16)r;
  x0[i] = b0; x1[i] = b1; x2[i] = (bf16)(r - (float)b1);
}

__global__ __launch_bounds__(256) void k_split3(const float* __restrict__ s,
                                                bf16* __restrict__ d0,
                                                bf16* __restrict__ d1,
                                                bf16* __restrict__ d2, long n8) {
  long i = (long)blockIdx.x * 256 + threadIdx.x;
  if (i >= n8) return;
  const float4* s4 = (const float4*)s;
  float4 a = s4[2 * i], b = s4[2 * i + 1];
  float vv[8] = {a.x, a.y, a.z, a.w, b.x, b.y, b.z, b.w};
  bf16x8 o0, o1, o2;
#pragma unroll
  for (int j = 0; j < 8; ++j) {
    float v = vv[j];
    bf16 h0 = (bf16)v;
    float r = v - (float)h0;
    bf16 h1 = (bf16)r;
    o0[j] = h0; o1[j] = h1; o2[j] = (bf16)(r - (float)h1);
  }
  ((bf16x8*)d0)[i] = o0;
  ((bf16x8*)d1)[i] = o1;
  ((bf16x8*)d2)[i] = o2;
}

__global__ __launch_bounds__(256) void k_headconv(const float* __restrict__ s,
                                                  bf16* __restrict__ d) {
  long i = (long)blockIdx.x * 256 + threadIdx.x;
  long n8 = (long)HROWS * DIMD / 8;
  if (i >= n8) return;
  long row = i / (DIMD / 8);
  bf16x8 o;
  if (row < VOCABN) {
    const float4* s4 = (const float4*)s;
    float4 a = s4[2 * i], b = s4[2 * i + 1];
    o[0] = (bf16)a.x; o[1] = (bf16)a.y; o[2] = (bf16)a.z; o[3] = (bf16)a.w;
    o[4] = (bf16)b.x; o[5] = (bf16)b.y; o[6] = (bf16)b.z; o[7] = (bf16)b.w;
  } else {
    o = (bf16x8)(bf16)0.f;
  }
  ((bf16x8*)d)[i] = o;
}

// Q,K 2-splits from f32 qkv (token layout); Q pre-scaled by 0.125 (exact)
__global__ __launch_bounds__(256) void k_qkprep(const float* __restrict__ qkv,
                                                bf16* __restrict__ q0,
                                                bf16* __restrict__ q1,
                                                bf16* __restrict__ k0,
                                                bf16* __restrict__ k1) {
  int i = blockIdx.x * 256 + threadIdx.x;  // [bh][q][d] flat
  if (i >= 16 * SEQ * HD) return;
  int d = i & 63, q = (i >> 6) & (SEQ - 1), bh = i >> 16;
  int b = bh >> 3, h = bh & 7;
  long src = ((long)(b * SEQ + q)) * (3 * DIMD) + h * HD + d;
  float qv = qkv[src] * 0.125f;
  float kv = qkv[src + DIMD];
  bf16 a = (bf16)qv; q0[i] = a; q1[i] = (bf16)(qv - (float)a);
  bf16 c = (bf16)kv; k0[i] = c; k1[i] = (bf16)(kv - (float)c);
}

// V^T 2-splits: vt[bh][d][k], rows padded to 128 per bh (pad never written)
__global__ __launch_bounds__(256) void k_vtprep(const float* __restrict__ qkv,
                                                bf16* __restrict__ vt0,
                                                bf16* __restrict__ vt1) {
  int i = blockIdx.x * 256 + threadIdx.x;  // [bh][d][k] flat
  if (i >= 16 * HD * SEQ) return;
  int k = i & (SEQ - 1), d = (i >> 10) & 63, bh = i >> 16;
  int b = bh >> 3, h = bh & 7;
  float v = qkv[((long)(b * SEQ + k)) * (3 * DIMD) + 2 * DIMD + h * HD + d];
  long dst = (long)bh * (128 * SEQ) + (long)d * SEQ + k;
  bf16 a = (bf16)v; vt0[dst] = a; vt1[dst] = (bf16)(v - (float)a);
}

// row softmax over P[16*SEQ][SEQ] f32 -> 2-split bf16 probabilities
__global__ __launch_bounds__(256) void k_softmax(const float* __restrict__ P,
                                                 bf16* __restrict__ p0,
                                                 bf16* __restrict__ p1) {
  int row = blockIdx.x;
  int t = threadIdx.x;
  const float* pr = P + (long)row * SEQ;
  __shared__ float red[256];
  float v[4];
  float m = -1e30f;
#pragma unroll
  for (int i = 0; i < 4; ++i) {
    v[i] = pr[t + i * 256];
    m = fmaxf(m, v[i]);
  }
  red[t] = m;
  __syncthreads();
  for (int off = 128; off; off >>= 1) {
    if (t < off) red[t] = fmaxf(red[t], red[t + off]);
    __syncthreads();
  }
  m = red[0];
  __syncthreads();
  float s = 0.f;
#pragma unroll
  for (int i = 0; i < 4; ++i) {
    v[i] = __expf(v[i] - m);
    s += v[i];
  }
  red[t] = s;
  __syncthreads();
  for (int off = 128; off; off >>= 1) {
    if (t < off) red[t] += red[t + off];
    __syncthreads();
  }
  float inv = 1.f / red[0];
#pragma unroll
  for (int i = 0; i < 4; ++i) {
    float p = v[i] * inv;
    long oi = (long)row * SEQ + t + i * 256;
    bf16 h0 = (bf16)p;
    p0[oi] = h0;
    p1[oi] = (bf16)(p - (float)h0);
  }
}

// attnf [bh][q][d] f32 -> token-layout 2-split at0/at1
__global__ __launch_bounds__(256) void k_atrepack(const float* __restrict__ attnf,
                                                  bf16* __restrict__ at0,
                                                  bf16* __restrict__ at1) {
  int i = blockIdx.x * 256 + threadIdx.x;
  if (i >= 16 * SEQ * HD) return;
  int d = i & 63, q = (i >> 6) & (SEQ - 1), bh = i >> 16;
  float v = attnf[i];
  long dst = ((long)((bh >> 3) * SEQ + q)) * DIMD + (bh & 7) * HD + d;
  bf16 a = (bf16)v;
  at0[dst] = a;
  at1[dst] = (bf16)(v - (float)a);
}

__global__ __launch_bounds__(64) void k_router(const float* __restrict__ x,
                                               const float* __restrict__ rw,
                                               const float* __restrict__ rb,
                                               float* __restrict__ cw) {
  int n = blockIdx.x;
  int t = threadIdx.x;
  int e = t >> 3, part = t & 7;
  __shared__ float red[64];
  const float* xr = x + (long)n * DIMD;
  const float* wr = rw + (long)e * DIMD;
  float d = 0.f;
  int c0 = part * 64;
#pragma unroll
  for (int c = 0; c < 64; c += 4) {
    float4 xv = *(const float4*)(xr + c0 + c);
    float4 wv = *(const float4*)(wr + c0 + c);
    d += xv.x * wv.x + xv.y * wv.y + xv.z * wv.z + xv.w * wv.w;
  }
  red[t] = d;
  __syncthreads();
  if (t < 8) {
    float logit = rb[t];
    for (int pp = 0; pp < 8; ++pp) logit += red[t * 8 + pp];
    red[t] = logit;
  }
  __syncthreads();
  if (t == 0) {
    float p2[8];
    float m = -1e30f;
    for (int i = 0; i < 8; ++i) m = fmaxf(m, red[i]);
    float s = 0.f;
    for (int i = 0; i < 8; ++i) { p2[i] = expf(red[i] - m); s += p2[i]; }
    for (int i = 0; i < 8; ++i) p2[i] /= s;
    int i1 = 0;
    for (int i = 1; i < 8; ++i) if (p2[i] > p2[i1]) i1 = i;
    int i2 = (i1 == 0) ? 1 : 0;
    for (int i = 0; i < 8; ++i) {
      if (i == i1 || i == i2) continue;
      if (p2[i] > p2[i2]) i2 = i;
    }
    float sum = p2[i1] + p2[i2] + 1e-8f;
    float o[8];
    for (int i = 0; i < 8; ++i) o[i] = 0.f;
    o[i1] = p2[i1] / sum;
    o[i2] = p2[i2] / sum;
    for (int i = 0; i < 8; ++i) cw[(long)n * 8 + i] = o[i];
  }
}

// BitNet: q in {-1,0,1} (exact bf16) + per-row f32 scale
__global__ __launch_bounds__(256) void k_bitw(const float* __restrict__ w,
                                              bf16* __restrict__ q,
                                              float* __restrict__ s, int cols) {
  int row = blockIdx.x;
  int t = threadIdx.x;
  const float* wr = w + (long)row * cols;
  float acc = 0.f;
  for (int c = t; c < cols; c += 256) acc += fabsf(wr[c]);
  __shared__ float red[256];
  red[t] = acc;
  __syncthreads();
  for (int off = 128; off; off >>= 1) {
    if (t < off) red[t] += red[t + off];
    __syncthreads();
  }
  float scale = fmaxf(red[0] / (float)cols, 1e-5f);
  if (t == 0) s[row] = scale;
  bf16* outr = q + (long)row * cols;
  for (int c = t; c < cols; c += 256) {
    float qv = rintf(wr[c] / scale);  // RNE, matches jnp.round
    qv = fmaxf(-1.f, fminf(1.f, qv));
    outr[c] = (bf16)qv;
  }
}

// combine top-2 experts, add residual, LayerNorm -> f32 + 3-split
__global__ __launch_bounds__(128) void k_lncomb(
    const float* __restrict__ yall, const float* __restrict__ cwp,
    const float* __restrict__ xBf, const float* __restrict__ g,
    const float* __restrict__ b, float* __restrict__ xof,
    bf16* __restrict__ x0, bf16* __restrict__ x1, bf16* __restrict__ x2) {
  int n = blockIdx.x;
  int t = threadIdx.x;
  __shared__ float red[128];
  float cw[8];
#pragma unroll
  for (int e = 0; e < 8; ++e) cw[e] = cwp[(long)n * 8 + e];
  float u[4];
  float s = 0.f;
#pragma unroll
  for (int i = 0; i < 4; ++i) {
    int d = t + i * 128;
    float v = xBf[(long)n * DIMD + d];
#pragma unroll
    for (int e = 0; e < 8; ++e)
      if (cw[e] != 0.f) v += cw[e] * yall[((long)e * NTOK + n) * DIMD + d];
    u[i] = v;
    s += v;
  }
  red[t] = s;
  __syncthreads();
  for (int off = 64; off; off >>= 1) {
    if (t < off) red[t] += red[t + off];
    __syncthreads();
  }
  float mu = red[0] / (float)DIMD;
  __syncthreads();
  float var = 0.f;
#pragma unroll
  for (int i = 0; i < 4; ++i) {
    float d = u[i] - mu;
    var += d * d;
  }
  red[t] = var;
  __syncthreads();
  for (int off = 64; off; off >>= 1) {
    if (t < off) red[t] += red[t + off];
    __syncthreads();
  }
  float inv = 1.f / sqrtf(red[0] / (float)DIMD + 1e-5f);
#pragma unroll
  for (int i = 0; i < 4; ++i) {
    int c = t + i * 128;
    float v = (u[i] - mu) * inv * g[c] + b[c];
    long oi = (long)n * DIMD + c;
    xof[oi] = v;
    bf16 b0 = (bf16)v;
    float r = v - (float)b0;
    bf16 b1 = (bf16)r;
    x0[oi] = b0; x1[oi] = b1; x2[oi] = (bf16)(r - (float)b1);
  }
}

extern "C" void kernel_launch(void* const* d_in, const int* in_sizes, int n_in,
                              void* d_out, int out_size, void* d_ws, size_t ws_size,
                              hipStream_t stream) {
  const int* ids = (const int*)d_in[0];
  const float* embed = (const float*)d_in[1];
  const float* qkv_w = (const float*)d_in[2];
  const float* out_w = (const float*)d_in[3];
  const float* router_w = (const float*)d_in[4];
  const float* router_b = (const float*)d_in[5];
  const float* w1 = (const float*)d_in[6];
  const float* b1 = (const float*)d_in[7];
  const float* w2 = (const float*)d_in[8];
  const float* b2 = (const float*)d_in[9];
  const float* ln_g = (const float*)d_in[10];
  const float* ln_b = (const float*)d_in[11];
  const float* head_w = (const float*)d_in[12];
  float* out = (float*)d_out;

  char* base = (char*)d_ws;
  size_t off = 0;
  auto alloc = [&](size_t bytes) -> void* {
    void* p = base + off;
    off += (bytes + 255) & ~(size_t)255;
    return p;
  };
  const size_t ND = (size_t)NTOK * DIMD;
  float* xAf = (float*)alloc(ND * 4);
  float* xBf = (float*)alloc(ND * 4);
  float* qkvb = (float*)alloc(ND * 3 * 4);
  float* cw = (float*)alloc((size_t)NTOK * EXPERTS * 4);
  bf16* xA0 = (bf16*)alloc(ND * 2);
  bf16* xA1 = (bf16*)alloc(ND * 2);
  bf16* xA2 = (bf16*)alloc(ND * 2);
  bf16* xB0 = (bf16*)alloc(ND * 2);
  bf16* xB1 = (bf16*)alloc(ND * 2);
  bf16* xB2 = (bf16*)alloc(ND * 2);
  bf16* at0 = (bf16*)alloc(ND * 2);
  bf16* at1 = (bf16*)alloc(ND * 2);
  bf16* qw0 = (bf16*)alloc((size_t)3 * DIMD * DIMD * 2);
  bf16* qw1 = (bf16*)alloc((size_t)3 * DIMD * DIMD * 2);
  bf16* qw2 = (bf16*)alloc((size_t)3 * DIMD * DIMD * 2);
  bf16* ow0 = (bf16*)alloc((size_t)DIMD * DIMD * 2);
  bf16* ow1 = (bf16*)alloc((size_t)DIMD * DIMD * 2);
  bf16* ow2 = (bf16*)alloc((size_t)DIMD * DIMD * 2);
  bf16* q0b = (bf16*)alloc((size_t)16 * SEQ * HD * 2);
  bf16* q1b = (bf16*)alloc((size_t)16 * SEQ * HD * 2);
  bf16* k0b = (bf16*)alloc((size_t)16 * SEQ * HD * 2);
  bf16* k1b = (bf16*)alloc((size_t)16 * SEQ * HD * 2);
  bf16* vt0b = (bf16*)alloc((size_t)16 * 128 * SEQ * 2);  // 128 rows: pad
  bf16* vt1b = (bf16*)alloc((size_t)16 * 128 * SEQ * 2);
  float* attnf = (float*)alloc((size_t)16 * SEQ * HD * 4);

  // ---- union region (time-multiplexed) ----
  size_t Ustart = off;
  // layout A: attention scores/probs
  float* Pbuf = (float*)(base + Ustart);
  bf16* p0b = (bf16*)(base + Ustart + ((size_t)64 << 20));
  bf16* p1b = (bf16*)(base + Ustart + ((size_t)96 << 20));
  size_t endA = Ustart + ((size_t)128 << 20);
  // layout B: expert scratch
  bf16* we1q = (bf16*)alloc((size_t)EXPERTS * FF * DIMD * 2);
  float* s1 = (float*)alloc((size_t)EXPERTS * FF * 4);
  bf16* we2q = (bf16*)alloc((size_t)EXPERTS * DIMD * FF * 2);
  float* s2 = (float*)alloc((size_t)EXPERTS * DIMD * 4);
  bf16* h0 = (bf16*)alloc((size_t)EXPERTS * NTOK * FF * 2);
  bf16* h1 = (bf16*)alloc((size_t)EXPERTS * NTOK * FF * 2);
  float* yall = (float*)alloc((size_t)EXPERTS * ND * 4);
  size_t endB = off;
  // layout C: head weights
  size_t endC = Ustart + (size_t)HROWS * DIMD * 2;
  bf16* hw0 = (bf16*)(base + Ustart);
  off = endA > endB ? endA : endB;
  if (endC > off) off = endC;
  if (ws_size < off) return;

  k_embed<<<(NTOK * DIMD + 255) / 256, 256, 0, stream>>>(ids, embed, xAf, xA0,
                                                         xA1, xA2);

  for (int l = 0; l < NLAYER; ++l) {
    const float* qw = qkv_w + (long)l * 3 * DIMD * DIMD;
    const float* ow = out_w + (long)l * DIMD * DIMD;
    long nq8 = (long)3 * DIMD * DIMD / 8;
    long no8 = (long)DIMD * DIMD / 8;
    k_split3<<<(int)((nq8 + 255) / 256), 256, 0, stream>>>(qw, qw0, qw1, qw2, nq8);
    k_split3<<<(int)((no8 + 255) / 256), 256, 0, stream>>>(ow, ow0, ow1, ow2, no8);
    // qkv = x @ qkv_w^T  (mode 1: ~f32, f32 out)
    k_mfma_gemm<<<dim3(NTOK / 128, (3 * DIMD) / 128, 1), 256, 0, stream>>>(
        xA0, xA1, xA2, qw0, qw1, qw2, qkvb, nullptr, nullptr, nullptr,
        NTOK, 3 * DIMD, DIMD, 0, 0, 0, 0, nullptr, 0, nullptr, 0, nullptr, 0, 1);
    // MFMA attention
    k_qkprep<<<(16 * SEQ * HD + 255) / 256, 256, 0, stream>>>(qkvb, q0b, q1b,
                                                              k0b, k1b);
    k_vtprep<<<(16 * HD * SEQ + 255) / 256, 256, 0, stream>>>(qkvb, vt0b, vt1b);
    // P = (Q*0.125) @ K^T   [bh][q][k]
    k_mfma_gemm<<<dim3(SEQ / 128, SEQ / 128, 16), 256, 0, stream>>>(
        q0b, q1b, nullptr, k0b, k1b, nullptr, Pbuf, nullptr, nullptr, nullptr,
        SEQ, SEQ, HD, (long)SEQ * HD, (long)SEQ * HD, (long)SEQ * SEQ, 0,
        nullptr, 0, nullptr, 0, nullptr, 0, 5);
    k_softmax<<<16 * SEQ, 256, 0, stream>>>(Pbuf, p0b, p1b);
    // O = P @ V   (B = V^T rows, padded to 128)
    k_mfma_gemm<<<dim3(SEQ / 128, 1, 16), 256, 0, stream>>>(
        p0b, p1b, nullptr, vt0b, vt1b, nullptr, attnf, nullptr, nullptr,
        nullptr, SEQ, HD, SEQ, (long)SEQ * SEQ, (long)128 * SEQ,
        (long)SEQ * HD, 0, nullptr, 0, nullptr, 0, nullptr, 0, 5);
    k_atrepack<<<(16 * SEQ * HD + 255) / 256, 256, 0, stream>>>(attnf, at0, at1);
    // xB = attn_o @ out_w^T + xA  (mode 4; f32 + 3-split out)
    k_mfma_gemm<<<dim3(NTOK / 128, DIMD / 128, 1), 256, 0, stream>>>(
        at0, at1, nullptr, ow0, ow1, ow2, xBf, xB0, xB1, xB2,
        NTOK, DIMD, DIMD, 0, 0, 0, 0, nullptr, 0, nullptr, 0, xAf, 0, 4);
    k_router<<<NTOK, 64, 0, stream>>>(xBf, router_w + (long)l * EXPERTS * DIMD,
                                      router_b + l * EXPERTS, cw);
    k_bitw<<<EXPERTS * FF, 256, 0, stream>>>(w1 + (long)l * EXPERTS * FF * DIMD,
                                             we1q, s1, DIMD);
    k_bitw<<<EXPERTS * DIMD, 256, 0, stream>>>(
        w2 + (long)l * EXPERTS * DIMD * FF, we2q, s2, FF);
    // h[e] = gelu((xB @ q1[e]^T)*s1 + b1)  (mode 2; 2-split bf16 out)
    k_mfma_gemm<<<dim3(NTOK / 128, FF / 128, EXPERTS), 256, 0, stream>>>(
        xB0, xB1, xB2, we1q, nullptr, nullptr, nullptr, h0, h1, nullptr,
        NTOK, FF, DIMD, 0, (long)FF * DIMD, 0, (long)NTOK * FF,
        s1, FF, b1 + (long)l * EXPERTS * FF, FF, nullptr, 1, 2);
    // y[e] = (h[e] @ q2[e]^T)*s2 + b2  (mode 3; f32 out)
    k_mfma_gemm<<<dim3(NTOK / 128, DIMD / 128, EXPERTS), 256, 0, stream>>>(
        h0, h1, nullptr, we2q, nullptr, nullptr, yall, nullptr, nullptr, nullptr,
        NTOK, DIMD, FF, (long)NTOK * FF, (long)DIMD * FF, (long)ND, 0,
        s2, DIMD, b2 + (long)l * EXPERTS * DIMD, DIMD, nullptr, 0, 3);
    k_lncomb<<<NTOK, 128, 0, stream>>>(yall, cw, xBf, ln_g + l * DIMD,
                                       ln_b + l * DIMD, xAf, xA0, xA1, xA2);
  }
  // head: logits = x @ head_w^T  (mode 0: plain bf16)
  long nh8 = (long)HROWS * DIMD / 8;
  k_headconv<<<(int)((nh8 + 255) / 256), 256, 0, stream>>>(head_w, hw0);
  k_mfma_gemm<<<dim3(NTOK / 128, HROWS / 128, 1), 256, 0, stream>>>(
      xA0, nullptr, nullptr, hw0, nullptr, nullptr, out, nullptr, nullptr,
      nullptr, NTOK, VOCABN, DIMD, 0, 0, 0, 0, nullptr, 0, nullptr, 0,
      nullptr, 0, 0);
}

// Round 5
// 2886.788 us; speedup vs baseline: 5.1315x; 1.0464x over previous
//
#include <hip/hip_runtime.h>
#include <math.h>
#include <stdint.h>

#define NLAYER 6
#define DIMD 512
#define HEADS 8
#define HD 64
#define EXPERTS 8
#define SEQ 1024
#define NTOK 2048
#define FF 1024
#define VOCABN 50257
#define HROWS 50304  // 393*128 zero-padded head rows

typedef __bf16 bf16;
typedef __bf16 bf16x8 __attribute__((ext_vector_type(8)));
typedef float f32x4 __attribute__((ext_vector_type(4)));

__device__ __forceinline__ void gl_lds16(const void* g, void* l) {
  __builtin_amdgcn_global_load_lds(
      (const __attribute__((address_space(1))) void*)(uintptr_t)g,
      (__attribute__((address_space(3))) void*)(uintptr_t)l, 16, 0, 0);
}

// LDS element offset for (row, 16B-chunk) with XOR swizzle (2-way conflicts)
#define LDSW(row, kg) (((row) * 32) + ((((kg) ^ (((row) >> 1) & 3))) << 3))

// ============ multi-pass split-bf16 MFMA GEMM: C = A @ Bt^T ============
// modes: 0:1p  1:6p(~f32 3x3)  2:3p(A3,Bexact)  3:2p(A2,Bexact)
//        4:5p(A2xB3)  5:3p(A2xB2)
// mLimit: per-z row count (blocks with m0>=mLimit[z] exit)
// aperm:  per-z A-row indirection table [z*2048 + row] (pad rows -> 2048)
__global__ __launch_bounds__(256) void k_mfma_gemm(
    const bf16* __restrict__ A0, const bf16* __restrict__ A1,
    const bf16* __restrict__ A2, const bf16* __restrict__ B0,
    const bf16* __restrict__ B1, const bf16* __restrict__ B2,
    float* __restrict__ Cf, bf16* __restrict__ Cb0, bf16* __restrict__ Cb1,
    bf16* __restrict__ Cb2, int M, int N, int K,
    long sA, long sB, long sCf, long sCb,
    const float* __restrict__ colScale, int csStride,
    const float* __restrict__ bias, int biasStride,
    const float* __restrict__ residual, int act, int mode,
    const int* __restrict__ mLimit, const int* __restrict__ aperm) {
  __shared__ __align__(16) bf16 As[128 * 32];
  __shared__ __align__(16) bf16 Bs[128 * 32];
  int tid = threadIdx.x;
  int z = blockIdx.z;
  // bijective XCD-aware swizzle (m204)
  int nwg = gridDim.x * gridDim.y;
  int flat = blockIdx.y * gridDim.x + blockIdx.x;
  int qq = nwg >> 3, rr = nwg & 7;
  int xcd = flat & 7, ii = flat >> 3;
  int swz = (xcd < rr ? xcd * (qq + 1) : rr * (qq + 1) + (xcd - rr) * qq) + ii;
  int m0 = (swz % gridDim.x) * 128, n0 = (swz / gridDim.x) * 128;
  if (mLimit && m0 >= mLimit[z]) return;
  int w = tid >> 6, lane = tid & 63;
  int wm = (w >> 1) * 64, wn = (w & 1) * 64;
  int r15 = lane & 15, kg = lane >> 4;

  const bf16* PA[3] = {A0, A1, A2};
  const bf16* PB[3] = {B0, B1, B2};
  int pa[6] = {0, 0, 0, 0, 0, 0};
  int pb[6] = {0, 0, 0, 0, 0, 0};
  int np = 1;
  if (mode == 1) {
    np = 6;
    pa[1] = 0; pb[1] = 1; pa[2] = 1; pb[2] = 0; pa[3] = 1; pb[3] = 1;
    pa[4] = 0; pb[4] = 2; pa[5] = 2; pb[5] = 0;
  } else if (mode == 2) {
    np = 3; pa[1] = 1; pa[2] = 2;
  } else if (mode == 3) {
    np = 2; pa[1] = 1;
  } else if (mode == 4) {
    np = 5;
    pa[1] = 0; pb[1] = 1; pa[2] = 1; pb[2] = 0; pa[3] = 0; pb[3] = 2;
    pa[4] = 1; pb[4] = 1;
  } else if (mode == 5) {
    np = 3;
    pa[1] = 0; pb[1] = 1; pa[2] = 1; pb[2] = 0;
  }

  f32x4 acc[4][4] = {};
  int srow = tid >> 2;
  // global source chunk pre-swizzled so linear LDS dest == swizzled layout
  int scol = (((tid & 3) ^ ((tid >> 3) & 3))) << 3;
  long arow0, arow1;
  if (aperm) {
    arow0 = aperm[z * 2048 + m0 + srow];
    arow1 = aperm[z * 2048 + m0 + 64 + srow];
  } else {
    arow0 = m0 + srow;
    arow1 = m0 + 64 + srow;
  }
  bf16* la0 = &As[tid * 8];
  bf16* la1 = &As[64 * 32 + tid * 8];
  bf16* lb0 = &Bs[tid * 8];
  bf16* lb1 = &Bs[64 * 32 + tid * 8];

  for (int p = 0; p < np; ++p) {
    const bf16* Az = PA[pa[p]] + (long)z * sA;
    const bf16* Bz = PB[pb[p]] + (long)z * sB;
    const bf16* ga0 = Az + arow0 * K + scol;
    const bf16* ga1 = Az + arow1 * K + scol;
    const bf16* gb0 = Bz + (long)(n0 + srow) * K + scol;
    const bf16* gb1 = Bz + (long)(n0 + 64 + srow) * K + scol;
    for (int k0 = 0; k0 < K; k0 += 32) {
      gl_lds16(ga0, la0);
      gl_lds16(ga1, la1);
      gl_lds16(gb0, lb0);
      gl_lds16(gb1, lb1);
      ga0 += 32; ga1 += 32; gb0 += 32; gb1 += 32;
      __syncthreads();  // drains vmcnt: tiles ready
      bf16x8 af[4], bfr[4];
#pragma unroll
      for (int mi = 0; mi < 4; ++mi) {
        int rowA = wm + mi * 16 + r15;
        af[mi] = *(const bf16x8*)&As[LDSW(rowA, kg)];
      }
#pragma unroll
      for (int ni = 0; ni < 4; ++ni) {
        int rowB = wn + ni * 16 + r15;
        bfr[ni] = *(const bf16x8*)&Bs[LDSW(rowB, kg)];
      }
#pragma unroll
      for (int mi = 0; mi < 4; ++mi)
#pragma unroll
        for (int ni = 0; ni < 4; ++ni)
          acc[mi][ni] = __builtin_amdgcn_mfma_f32_16x16x32_bf16(
              af[mi], bfr[ni], acc[mi][ni], 0, 0, 0);
      __syncthreads();  // reads done before next overwrite
    }
  }

  // C/D layout: col=lane&15, row=(lane>>4)*4+reg  [m89]
#pragma unroll
  for (int mi = 0; mi < 4; ++mi) {
    int rbase = m0 + wm + mi * 16 + kg * 4;
#pragma unroll
    for (int ni = 0; ni < 4; ++ni) {
      int col = n0 + wn + ni * 16 + r15;
      if (col >= N) continue;
      float scl = colScale ? colScale[z * csStride + col] : 1.f;
      float bv = bias ? bias[z * biasStride + col] : 0.f;
#pragma unroll
      for (int reg = 0; reg < 4; ++reg) {
        int row = rbase + reg;
        float v = acc[mi][ni][reg] * scl + bv;
        if (act) v = 0.5f * v * (1.f + erff(v * 0.70710678118654752f));
        if (residual) v += residual[(long)row * N + col];
        long ci = (long)row * N + col;
        if (Cf) Cf[z * sCf + ci] = v;
        if (Cb0) {
          bf16 h0 = (bf16)v;
          Cb0[z * sCb + ci] = h0;
          if (Cb1) {
            float r = v - (float)h0;
            bf16 h1 = (bf16)r;
            Cb1[z * sCb + ci] = h1;
            if (Cb2) Cb2[z * sCb + ci] = (bf16)(r - (float)h1);
          }
        }
      }
    }
  }
}

// ---------------- helpers ----------------
__global__ __launch_bounds__(256) void k_embed(const int* __restrict__ ids,
                                               const float* __restrict__ E,
                                               float* __restrict__ xf,
                                               bf16* __restrict__ x0,
                                               bf16* __restrict__ x1,
                                               bf16* __restrict__ x2) {
  int i = blockIdx.x * 256 + threadIdx.x;
  if (i >= NTOK * DIMD) return;
  int n = i >> 9, d = i & 511;
  float v = E[(long)ids[n] * DIMD + d];
  xf[i] = v;
  bf16 b0 = (bf16)v;
  float r = v - (float)b0;
  bf16 b1 = (bf16)r;
  x0[i] = b0; x1[i] = b1; x2[i] = (bf16)(r - (float)b1);
}

__global__ __launch_bounds__(256) void k_split3(const float* __restrict__ s,
                                                bf16* __restrict__ d0,
                                                bf16* __restrict__ d1,
                                                bf16* __restrict__ d2, long n8) {
  long i = (long)blockIdx.x * 256 + threadIdx.x;
  if (i >= n8) return;
  const float4* s4 = (const float4*)s;
  float4 a = s4[2 * i], b = s4[2 * i + 1];
  float vv[8] = {a.x, a.y, a.z, a.w, b.x, b.y, b.z, b.w};
  bf16x8 o0, o1, o2;
#pragma unroll
  for (int j = 0; j < 8; ++j) {
    float v = vv[j];
    bf16 h0 = (bf16)v;
    float r = v - (float)h0;
    bf16 h1 = (bf16)r;
    o0[j] = h0; o1[j] = h1; o2[j] = (bf16)(r - (float)h1);
  }
  ((bf16x8*)d0)[i] = o0;
  ((bf16x8*)d1)[i] = o1;
  ((bf16x8*)d2)[i] = o2;
}

__global__ __launch_bounds__(256) void k_headconv(const float* __restrict__ s,
                                                  bf16* __restrict__ d) {
  long i = (long)blockIdx.x * 256 + threadIdx.x;
  long n8 = (long)HROWS * DIMD / 8;
  if (i >= n8) return;
  long row = i / (DIMD / 8);
  bf16x8 o;
  if (row < VOCABN) {
    const float4* s4 = (const float4*)s;
    float4 a = s4[2 * i], b = s4[2 * i + 1];
    o[0] = (bf16)a.x; o[1] = (bf16)a.y; o[2] = (bf16)a.z; o[3] = (bf16)a.w;
    o[4] = (bf16)b.x; o[5] = (bf16)b.y; o[6] = (bf16)b.z; o[7] = (bf16)b.w;
  } else {
    o = (bf16x8)(bf16)0.f;
  }
  ((bf16x8*)d)[i] = o;
}

// Q,K 2-splits from f32 qkv (token layout); Q pre-scaled by 0.125 (exact)
__global__ __launch_bounds__(256) void k_qkprep(const float* __restrict__ qkv,
                                                bf16* __restrict__ q0,
                                                bf16* __restrict__ q1,
                                                bf16* __restrict__ k0,
                                                bf16* __restrict__ k1) {
  int i = blockIdx.x * 256 + threadIdx.x;  // [bh][q][d] flat
  if (i >= 16 * SEQ * HD) return;
  int d = i & 63, q = (i >> 6) & (SEQ - 1), bh = i >> 16;
  int b = bh >> 3, h = bh & 7;
  long src = ((long)(b * SEQ + q)) * (3 * DIMD) + h * HD + d;
  float qv = qkv[src] * 0.125f;
  float kv = qkv[src + DIMD];
  bf16 a = (bf16)qv; q0[i] = a; q1[i] = (bf16)(qv - (float)a);
  bf16 c = (bf16)kv; k0[i] = c; k1[i] = (bf16)(kv - (float)c);
}

// V^T 2-splits: vt[bh][d][k], rows padded to 128 per bh (pad never written)
__global__ __launch_bounds__(256) void k_vtprep(const float* __restrict__ qkv,
                                                bf16* __restrict__ vt0,
                                                bf16* __restrict__ vt1) {
  int i = blockIdx.x * 256 + threadIdx.x;  // [bh][d][k] flat
  if (i >= 16 * HD * SEQ) return;
  int k = i & (SEQ - 1), d = (i >> 10) & 63, bh = i >> 16;
  int b = bh >> 3, h = bh & 7;
  float v = qkv[((long)(b * SEQ + k)) * (3 * DIMD) + 2 * DIMD + h * HD + d];
  long dst = (long)bh * (128 * SEQ) + (long)d * SEQ + k;
  bf16 a = (bf16)v; vt0[dst] = a; vt1[dst] = (bf16)(v - (float)a);
}

// row softmax over P[16*SEQ][SEQ] f32 -> 2-split bf16 probabilities
__global__ __launch_bounds__(256) void k_softmax(const float* __restrict__ P,
                                                 bf16* __restrict__ p0,
                                                 bf16* __restrict__ p1) {
  int row = blockIdx.x;
  int t = threadIdx.x;
  const float* pr = P + (long)row * SEQ;
  __shared__ float red[256];
  float v[4];
  float m = -1e30f;
#pragma unroll
  for (int i = 0; i < 4; ++i) {
    v[i] = pr[t + i * 256];
    m = fmaxf(m, v[i]);
  }
  red[t] = m;
  __syncthreads();
  for (int off = 128; off; off >>= 1) {
    if (t < off) red[t] = fmaxf(red[t], red[t + off]);
    __syncthreads();
  }
  m = red[0];
  __syncthreads();
  float s = 0.f;
#pragma unroll
  for (int i = 0; i < 4; ++i) {
    v[i] = __expf(v[i] - m);
    s += v[i];
  }
  red[t] = s;
  __syncthreads();
  for (int off = 128; off; off >>= 1) {
    if (t < off) red[t] += red[t + off];
    __syncthreads();
  }
  float inv = 1.f / red[0];
#pragma unroll
  for (int i = 0; i < 4; ++i) {
    float p = v[i] * inv;
    long oi = (long)row * SEQ + t + i * 256;
    bf16 h0 = (bf16)p;
    p0[oi] = h0;
    p1[oi] = (bf16)(p - (float)h0);
  }
}

// attnf [bh][q][d] f32 -> token-layout 2-split at0/at1
__global__ __launch_bounds__(256) void k_atrepack(const float* __restrict__ attnf,
                                                  bf16* __restrict__ at0,
                                                  bf16* __restrict__ at1) {
  int i = blockIdx.x * 256 + threadIdx.x;
  if (i >= 16 * SEQ * HD) return;
  int d = i & 63, q = (i >> 6) & (SEQ - 1), bh = i >> 16;
  float v = attnf[i];
  long dst = ((long)((bh >> 3) * SEQ + q)) * DIMD + (bh & 7) * HD + d;
  bf16 a = (bf16)v;
  at0[dst] = a;
  at1[dst] = (bf16)(v - (float)a);
}

// router: top-2 expert ids + normalized weights per token
__global__ __launch_bounds__(64) void k_router(const float* __restrict__ x,
                                               const float* __restrict__ rw,
                                               const float* __restrict__ rb,
                                               int* __restrict__ top2,
                                               float* __restrict__ v2) {
  int n = blockIdx.x;
  int t = threadIdx.x;
  int e = t >> 3, part = t & 7;
  __shared__ float red[64];
  const float* xr = x + (long)n * DIMD;
  const float* wr = rw + (long)e * DIMD;
  float d = 0.f;
  int c0 = part * 64;
#pragma unroll
  for (int c = 0; c < 64; c += 4) {
    float4 xv = *(const float4*)(xr + c0 + c);
    float4 wv = *(const float4*)(wr + c0 + c);
    d += xv.x * wv.x + xv.y * wv.y + xv.z * wv.z + xv.w * wv.w;
  }
  red[t] = d;
  __syncthreads();
  if (t < 8) {
    float logit = rb[t];
    for (int pp = 0; pp < 8; ++pp) logit += red[t * 8 + pp];
    red[t] = logit;
  }
  __syncthreads();
  if (t == 0) {
    float p2[8];
    float m = -1e30f;
    for (int i = 0; i < 8; ++i) m = fmaxf(m, red[i]);
    float s = 0.f;
    for (int i = 0; i < 8; ++i) { p2[i] = expf(red[i] - m); s += p2[i]; }
    for (int i = 0; i < 8; ++i) p2[i] /= s;
    int i1 = 0;
    for (int i = 1; i < 8; ++i) if (p2[i] > p2[i1]) i1 = i;
    int i2 = (i1 == 0) ? 1 : 0;
    for (int i = 0; i < 8; ++i) {
      if (i == i1 || i == i2) continue;
      if (p2[i] > p2[i2]) i2 = i;
    }
    float sum = p2[i1] + p2[i2] + 1e-8f;
    top2[2 * n] = i1;
    top2[2 * n + 1] = i2;
    v2[2 * n] = p2[i1] / sum;
    v2[2 * n + 1] = p2[i2] / sum;
  }
}

// per-expert deterministic token lists via block prefix scan; also zeroes
// the shared zero-row (row 2048 of xB splits) used for pad rows
__global__ __launch_bounds__(256) void k_expcnt(const int* __restrict__ top2,
                                                int* __restrict__ perm,
                                                int* __restrict__ tokpos,
                                                int* __restrict__ cnt,
                                                bf16* __restrict__ zx0,
                                                bf16* __restrict__ zx1,
                                                bf16* __restrict__ zx2) {
  int e = blockIdx.x, t = threadIdx.x;
  if (e == 0) {
    for (int c = t; c < DIMD; c += 256) {
      zx0[c] = (bf16)0.f; zx1[c] = (bf16)0.f; zx2[c] = (bf16)0.f;
    }
  }
  __shared__ int sc[256];
  int base = 0;
  for (int c0 = 0; c0 < NTOK; c0 += 256) {
    int n = c0 + t;
    int f = (top2[2 * n] == e || top2[2 * n + 1] == e) ? 1 : 0;
    sc[t] = f;
    __syncthreads();
    for (int o = 1; o < 256; o <<= 1) {
      int v = (t >= o) ? sc[t - o] : 0;
      __syncthreads();
      sc[t] += v;
      __syncthreads();
    }
    if (f) {
      int pos = base + sc[t] - 1;
      perm[e * 2048 + pos] = n;
      int j = (top2[2 * n] == e) ? 0 : 1;
      tokpos[2 * n + j] = e * 2048 + pos;
    }
    base += sc[255];
    __syncthreads();
  }
  int cpad = (base + 127) & ~127;
  for (int i = base + t; i < cpad; i += 256) perm[e * 2048 + i] = 2048;
  if (t == 0) cnt[e] = base;
}

// BitNet: q in {-1,0,1} (exact bf16) + per-row f32 scale
__global__ __launch_bounds__(256) void k_bitw(const float* __restrict__ w,
                                              bf16* __restrict__ q,
                                              float* __restrict__ s, int cols) {
  int row = blockIdx.x;
  int t = threadIdx.x;
  const float* wr = w + (long)row * cols;
  float acc = 0.f;
  for (int c = t; c < cols; c += 256) acc += fabsf(wr[c]);
  __shared__ float red[256];
  red[t] = acc;
  __syncthreads();
  for (int off = 128; off; off >>= 1) {
    if (t < off) red[t] += red[t + off];
    __syncthreads();
  }
  float scale = fmaxf(red[0] / (float)cols, 1e-5f);
  if (t == 0) s[row] = scale;
  bf16* outr = q + (long)row * cols;
  for (int c = t; c < cols; c += 256) {
    float qv = rintf(wr[c] / scale);  // RNE, matches jnp.round
    qv = fmaxf(-1.f, fminf(1.f, qv));
    outr[c] = (bf16)qv;
  }
}

// combine top-2 experts (gathered f32 y), add residual, LN -> f32 + 3-split
__global__ __launch_bounds__(128) void k_lncomb(
    const float* __restrict__ yg, const int* __restrict__ tokpos,
    const float* __restrict__ v2, const float* __restrict__ xBf,
    const float* __restrict__ g, const float* __restrict__ b,
    float* __restrict__ xof, bf16* __restrict__ x0, bf16* __restrict__ x1,
    bf16* __restrict__ x2) {
  int n = blockIdx.x;
  int t = threadIdx.x;
  __shared__ float red[128];
  long tp0 = tokpos[2 * n], tp1 = tokpos[2 * n + 1];
  float w0 = v2[2 * n], w1 = v2[2 * n + 1];
  const float* y0 = yg + tp0 * DIMD;
  const float* y1 = yg + tp1 * DIMD;
  float u[4];
  float s = 0.f;
#pragma unroll
  for (int i = 0; i < 4; ++i) {
    int d = t + i * 128;
    float v = xBf[(long)n * DIMD + d] + w0 * y0[d] + w1 * y1[d];
    u[i] = v;
    s += v;
  }
  red[t] = s;
  __syncthreads();
  for (int off = 64; off; off >>= 1) {
    if (t < off) red[t] += red[t + off];
    __syncthreads();
  }
  float mu = red[0] / (float)DIMD;
  __syncthreads();
  float var = 0.f;
#pragma unroll
  for (int i = 0; i < 4; ++i) {
    float d = u[i] - mu;
    var += d * d;
  }
  red[t] = var;
  __syncthreads();
  for (int off = 64; off; off >>= 1) {
    if (t < off) red[t] += red[t + off];
    __syncthreads();
  }
  float inv = 1.f / sqrtf(red[0] / (float)DIMD + 1e-5f);
#pragma unroll
  for (int i = 0; i < 4; ++i) {
    int c = t + i * 128;
    float v = (u[i] - mu) * inv * g[c] + b[c];
    long oi = (long)n * DIMD + c;
    xof[oi] = v;
    bf16 b0 = (bf16)v;
    float r = v - (float)b0;
    bf16 b1 = (bf16)r;
    x0[oi] = b0; x1[oi] = b1; x2[oi] = (bf16)(r - (float)b1);
  }
}

extern "C" void kernel_launch(void* const* d_in, const int* in_sizes, int n_in,
                              void* d_out, int out_size, void* d_ws, size_t ws_size,
                              hipStream_t stream) {
  const int* ids = (const int*)d_in[0];
  const float* embed = (const float*)d_in[1];
  const float* qkv_w = (const float*)d_in[2];
  const float* out_w = (const float*)d_in[3];
  const float* router_w = (const float*)d_in[4];
  const float* router_b = (const float*)d_in[5];
  const float* w1 = (const float*)d_in[6];
  const float* b1 = (const float*)d_in[7];
  const float* w2 = (const float*)d_in[8];
  const float* b2 = (const float*)d_in[9];
  const float* ln_g = (const float*)d_in[10];
  const float* ln_b = (const float*)d_in[11];
  const float* head_w = (const float*)d_in[12];
  float* out = (float*)d_out;

  char* base = (char*)d_ws;
  size_t off = 0;
  auto alloc = [&](size_t bytes) -> void* {
    void* p = base + off;
    off += (bytes + 255) & ~(size_t)255;
    return p;
  };
  const size_t ND = (size_t)NTOK * DIMD;
  float* xAf = (float*)alloc(ND * 4);
  float* xBf = (float*)alloc(ND * 4);
  float* qkvb = (float*)alloc(ND * 3 * 4);
  int* top2 = (int*)alloc((size_t)NTOK * 2 * 4);
  float* v2 = (float*)alloc((size_t)NTOK * 2 * 4);
  int* perm = (int*)alloc((size_t)EXPERTS * 2048 * 4);
  int* tokpos = (int*)alloc((size_t)NTOK * 2 * 4);
  int* cntb = (int*)alloc(64);
  bf16* xA0 = (bf16*)alloc(ND * 2);
  bf16* xA1 = (bf16*)alloc(ND * 2);
  bf16* xA2 = (bf16*)alloc(ND * 2);
  bf16* xB0 = (bf16*)alloc((ND + DIMD) * 2);  // +1 zero row (idx 2048)
  bf16* xB1 = (bf16*)alloc((ND + DIMD) * 2);
  bf16* xB2 = (bf16*)alloc((ND + DIMD) * 2);
  bf16* at0 = (bf16*)alloc(ND * 2);
  bf16* at1 = (bf16*)alloc(ND * 2);
  bf16* qw0 = (bf16*)alloc((size_t)3 * DIMD * DIMD * 2);
  bf16* qw1 = (bf16*)alloc((size_t)3 * DIMD * DIMD * 2);
  bf16* qw2 = (bf16*)alloc((size_t)3 * DIMD * DIMD * 2);
  bf16* ow0 = (bf16*)alloc((size_t)DIMD * DIMD * 2);
  bf16* ow1 = (bf16*)alloc((size_t)DIMD * DIMD * 2);
  bf16* ow2 = (bf16*)alloc((size_t)DIMD * DIMD * 2);
  bf16* q0b = (bf16*)alloc((size_t)16 * SEQ * HD * 2);
  bf16* q1b = (bf16*)alloc((size_t)16 * SEQ * HD * 2);
  bf16* k0b = (bf16*)alloc((size_t)16 * SEQ * HD * 2);
  bf16* k1b = (bf16*)alloc((size_t)16 * SEQ * HD * 2);
  bf16* vt0b = (bf16*)alloc((size_t)16 * 128 * SEQ * 2);  // 128 rows: pad
  bf16* vt1b = (bf16*)alloc((size_t)16 * 128 * SEQ * 2);
  float* attnf = (float*)alloc((size_t)16 * SEQ * HD * 4);

  // ---- union region (time-multiplexed) ----
  size_t Ustart = off;
  // layout A: attention scores/probs
  float* Pbuf = (float*)(base + Ustart);
  bf16* p0b = (bf16*)(base + Ustart + ((size_t)64 << 20));
  bf16* p1b = (bf16*)(base + Ustart + ((size_t)96 << 20));
  size_t endA = Ustart + ((size_t)128 << 20);
  // layout B: expert scratch (gathered layouts, 2048 rows/expert stride)
  bf16* we1q = (bf16*)alloc((size_t)EXPERTS * FF * DIMD * 2);
  float* s1 = (float*)alloc((size_t)EXPERTS * FF * 4);
  bf16* we2q = (bf16*)alloc((size_t)EXPERTS * DIMD * FF * 2);
  float* s2 = (float*)alloc((size_t)EXPERTS * DIMD * 4);
  bf16* h0g = (bf16*)alloc((size_t)EXPERTS * 2048 * FF * 2);
  bf16* h1g = (bf16*)alloc((size_t)EXPERTS * 2048 * FF * 2);
  float* yg = (float*)alloc((size_t)EXPERTS * 2048 * DIMD * 4);
  size_t endB = off;
  // layout C: head weights
  size_t endC = Ustart + (size_t)HROWS * DIMD * 2;
  bf16* hw0 = (bf16*)(base + Ustart);
  off = endA > endB ? endA : endB;
  if (endC > off) off = endC;
  if (ws_size < off) return;

  k_embed<<<(NTOK * DIMD + 255) / 256, 256, 0, stream>>>(ids, embed, xAf, xA0,
                                                         xA1, xA2);

  for (int l = 0; l < NLAYER; ++l) {
    const float* qw = qkv_w + (long)l * 3 * DIMD * DIMD;
    const float* ow = out_w + (long)l * DIMD * DIMD;
    long nq8 = (long)3 * DIMD * DIMD / 8;
    long no8 = (long)DIMD * DIMD / 8;
    k_split3<<<(int)((nq8 + 255) / 256), 256, 0, stream>>>(qw, qw0, qw1, qw2, nq8);
    k_split3<<<(int)((no8 + 255) / 256), 256, 0, stream>>>(ow, ow0, ow1, ow2, no8);
    // qkv = x @ qkv_w^T  (mode 1: ~f32, f32 out)
    k_mfma_gemm<<<dim3(NTOK / 128, (3 * DIMD) / 128, 1), 256, 0, stream>>>(
        xA0, xA1, xA2, qw0, qw1, qw2, qkvb, nullptr, nullptr, nullptr,
        NTOK, 3 * DIMD, DIMD, 0, 0, 0, 0, nullptr, 0, nullptr, 0, nullptr, 0,
        1, nullptr, nullptr);
    // MFMA attention
    k_qkprep<<<(16 * SEQ * HD + 255) / 256, 256, 0, stream>>>(qkvb, q0b, q1b,
                                                              k0b, k1b);
    k_vtprep<<<(16 * HD * SEQ + 255) / 256, 256, 0, stream>>>(qkvb, vt0b, vt1b);
    // P = (Q*0.125) @ K^T   [bh][q][k]
    k_mfma_gemm<<<dim3(SEQ / 128, SEQ / 128, 16), 256, 0, stream>>>(
        q0b, q1b, nullptr, k0b, k1b, nullptr, Pbuf, nullptr, nullptr, nullptr,
        SEQ, SEQ, HD, (long)SEQ * HD, (long)SEQ * HD, (long)SEQ * SEQ, 0,
        nullptr, 0, nullptr, 0, nullptr, 0, 5, nullptr, nullptr);
    k_softmax<<<16 * SEQ, 256, 0, stream>>>(Pbuf, p0b, p1b);
    // O = P @ V   (B = V^T rows, padded to 128)
    k_mfma_gemm<<<dim3(SEQ / 128, 1, 16), 256, 0, stream>>>(
        p0b, p1b, nullptr, vt0b, vt1b, nullptr, attnf, nullptr, nullptr,
        nullptr, SEQ, HD, SEQ, (long)SEQ * SEQ, (long)128 * SEQ,
        (long)SEQ * HD, 0, nullptr, 0, nullptr, 0, nullptr, 0, 5,
        nullptr, nullptr);
    k_atrepack<<<(16 * SEQ * HD + 255) / 256, 256, 0, stream>>>(attnf, at0, at1);
    // xB = attn_o @ out_w^T + xA  (mode 4; f32 + 3-split out)
    k_mfma_gemm<<<dim3(NTOK / 128, DIMD / 128, 1), 256, 0, stream>>>(
        at0, at1, nullptr, ow0, ow1, ow2, xBf, xB0, xB1, xB2,
        NTOK, DIMD, DIMD, 0, 0, 0, 0, nullptr, 0, nullptr, 0, xAf, 0, 4,
        nullptr, nullptr);
    k_router<<<NTOK, 64, 0, stream>>>(xBf, router_w + (long)l * EXPERTS * DIMD,
                                      router_b + l * EXPERTS, top2, v2);
    k_expcnt<<<EXPERTS, 256, 0, stream>>>(top2, perm, tokpos, cntb,
                                          xB0 + ND, xB1 + ND, xB2 + ND);
    k_bitw<<<EXPERTS * FF, 256, 0, stream>>>(w1 + (long)l * EXPERTS * FF * DIMD,
                                             we1q, s1, DIMD);
    k_bitw<<<EXPERTS * DIMD, 256, 0, stream>>>(
        w2 + (long)l * EXPERTS * DIMD * FF, we2q, s2, FF);
    // h[e] = gelu((gather(xB) @ q1[e]^T)*s1 + b1)  (mode 2, A-perm, sparse)
    k_mfma_gemm<<<dim3(NTOK / 128, FF / 128, EXPERTS), 256, 0, stream>>>(
        xB0, xB1, xB2, we1q, nullptr, nullptr, nullptr, h0g, h1g, nullptr,
        NTOK, FF, DIMD, 0, (long)FF * DIMD, 0, (long)2048 * FF,
        s1, FF, b1 + (long)l * EXPERTS * FF, FF, nullptr, 1, 2, cntb, perm);
    // y[e] = (h[e] @ q2[e]^T)*s2 + b2  (mode 3, sparse, f32 out)
    k_mfma_gemm<<<dim3(NTOK / 128, DIMD / 128, EXPERTS), 256, 0, stream>>>(
        h0g, h1g, nullptr, we2q, nullptr, nullptr, yg, nullptr, nullptr,
        nullptr, NTOK, DIMD, FF, (long)2048 * FF, (long)DIMD * FF,
        (long)2048 * DIMD, 0, s2, DIMD, b2 + (long)l * EXPERTS * DIMD, DIMD,
        nullptr, 0, 3, cntb, nullptr);
    k_lncomb<<<NTOK, 128, 0, stream>>>(yg, tokpos, v2, xBf, ln_g + l * DIMD,
                                       ln_b + l * DIMD, xAf, xA0, xA1, xA2);
  }
  // head: logits = x @ head_w^T  (mode 0: plain bf16)
  long nh8 = (long)HROWS * DIMD / 8;
  k_headconv<<<(int)((nh8 + 255) / 256), 256, 0, stream>>>(head_w, hw0);
  k_mfma_gemm<<<dim3(NTOK / 128, HROWS / 128, 1), 256, 0, stream>>>(
      xA0, nullptr, nullptr, hw0, nullptr, nullptr, out, nullptr, nullptr,
      nullptr, NTOK, VOCABN, DIMD, 0, 0, 0, 0, nullptr, 0, nullptr, 0,
      nullptr, 0, 0, nullptr, nullptr);
}